// Round 23
// baseline (53.665 us; speedup 1.0000x reference)
//
#include <hip/hip_runtime.h>
#include <hip/hip_fp16.h>
#include <math.h>

#define CLIPV 0.03f

struct W9 { float g[9]; };
struct half4 { __half2 a, b; };   // 8 bytes, 2 VGPRs

__device__ __forceinline__ int reflect_idx(int i, int n) {
    if (i < 0) i = -i;
    if (i >= n) i = 2 * n - 2 - i;
    return i;
}

__device__ __forceinline__ float4 h4_to_f4(half4 v) {
    const float2 ab = __half22float2(v.a), cd = __half22float2(v.b);
    float4 r; r.x = ab.x; r.y = ab.y; r.z = cd.x; r.w = cd.y; return r;
}
__device__ __forceinline__ half4 f4_to_h4(float4 v) {
    half4 r; r.a = __floats2half2_rn(v.x, v.y); r.b = __floats2half2_rn(v.z, v.w);
    return r;
}

// ---------------------------------------------------------------------------
// Pass 1: H-conv march + in-block W via LDS tile (x f32 -> t2 fp16).
// Phase A (per wave, == the 9-us h_pass shape): march 24 rows with ONE
// contiguous f4 load/iter + 9-ring, H-conv, ds_write half4 result into the
// block tile (NO global store in the march — the HBM-facing loop carries
// zero W machinery, the invariant all 41-us variants violated).
// __syncthreads (real barrier).
// Phase B: per lane, 3x ds_read_b64 window from the tile (2-way alias =
// free), W-conv, coalesced half4 store. Edge lanes: dummy-aligned A/C +
// select table (R22-validated structure, tile-local cols).
// Block = 64 rows x 256 cols of one plane; 4 waves x 16 rows.
// Grid: 1024 blocks x 256 thr = 16 waves/CU; bid&7 = XCD z-band.
// LDS: 64 x 264 halfs = 33 KB -> 4 blocks/CU.
// ---------------------------------------------------------------------------
__global__ __launch_bounds__(256) void wh_pass(const float* __restrict__ x,
                                               __half* __restrict__ t2, W9 wt) {
    __shared__ __half tile[64][264];   // cols 0..255 used; stride 264 halfs

    const int bid = blockIdx.x;
    const int xcd = bid & 7;
    const int k   = bid >> 3;              // 0..127
    const int z   = xcd * 32 + (k >> 2);   // XCD-local z band
    const int rb  = (k & 3) * 64;          // block row base
    const int wv  = threadIdx.x >> 6;
    const int h0  = rb + wv * 16;          // this wave's 16 output rows
    const int L   = threadIdx.x & 63;
    const int w4  = L * 4;

    const float* plane = x + (size_t)z * 65536;

    // ---- Phase A: H-conv march (proven shape), results -> LDS tile ----
    {
        float4 ring[9];
        float4 cur = *(const float4*)(plane + (size_t)reflect_idx(h0 - 4, 256) * 256 + w4);
        float4 nxt = *(const float4*)(plane + (size_t)reflect_idx(h0 - 3, 256) * 256 + w4);

        #pragma unroll
        for (int i = 0; i < 24; ++i) {
            float4 nn;
            if (i < 22)
                nn = *(const float4*)(plane + (size_t)reflect_idx(h0 - 2 + i, 256) * 256 + w4);

            ring[i % 9] = cur;   // raw row h0-4+i (static index after unroll)

            if (i >= 8) {
                float a0 = 0.f, a1 = 0.f, a2 = 0.f, a3 = 0.f;
                #pragma unroll
                for (int j = 0; j < 9; ++j) {
                    const float4 v = ring[(i - 8 + j) % 9];
                    a0 = fmaf(wt.g[j], v.x, a0);
                    a1 = fmaf(wt.g[j], v.y, a1);
                    a2 = fmaf(wt.g[j], v.z, a2);
                    a3 = fmaf(wt.g[j], v.w, a3);
                }
                float4 o; o.x = a0; o.y = a1; o.z = a2; o.w = a3;
                *(half4*)&tile[wv * 16 + (i - 8)][w4] = f4_to_h4(o);
            }

            cur = nxt; nxt = nn;
        }
    }
    __syncthreads();

    // ---- Phase B: W-conv from the tile, coalesced stores ----
    __half* oplane = t2 + (size_t)z * 65536 + (size_t)rb * 256;
    const bool l0 = (L == 0), l63 = (L == 63);
    const int offA = l0  ? w4 : (w4 - 4);   // lane 0: dummy (== B)
    const int offC = l63 ? w4 : (w4 + 4);   // lane 63: dummy (== B)

    #pragma unroll
    for (int s = 0; s < 16; ++s) {
        const int r = wv * 16 + s;
        const float4 A = h4_to_f4(*(const half4*)&tile[r][offA]);
        const float4 B = h4_to_f4(*(const half4*)&tile[r][w4]);
        const float4 C = h4_to_f4(*(const half4*)&tile[r][offC]);

        float sv[12];
        sv[0] = l0 ? C.x : A.x;   // col -4 -> 4  (lane0: C = cols 4..7)
        sv[1] = l0 ? B.w : A.y;   // col -3 -> 3
        sv[2] = l0 ? B.z : A.z;   // col -2 -> 2
        sv[3] = l0 ? B.y : A.w;   // col -1 -> 1
        sv[4] = B.x; sv[5] = B.y; sv[6] = B.z; sv[7] = B.w;
        sv[8]  = l63 ? B.z : C.x; // col 256 -> 254
        sv[9]  = l63 ? B.y : C.y; // col 257 -> 253
        sv[10] = l63 ? B.x : C.z; // col 258 -> 252
        sv[11] = l63 ? A.w : C.w; // col 259 -> 251 (lane63: A = 248..251)

        float a0 = 0.f, a1 = 0.f, a2 = 0.f, a3 = 0.f;
        #pragma unroll
        for (int j = 0; j < 9; ++j) {
            a0 = fmaf(wt.g[j], sv[j],     a0);
            a1 = fmaf(wt.g[j], sv[j + 1], a1);
            a2 = fmaf(wt.g[j], sv[j + 2], a2);
            a3 = fmaf(wt.g[j], sv[j + 3], a3);
        }
        float4 o; o.x = a0; o.y = a1; o.z = a2; o.w = a3;
        *(half4*)(oplane + (size_t)r * 256 + w4) = f4_to_h4(o);
    }
}

// ---------------------------------------------------------------------------
// Pass 2: D-conv + clip (t2 fp16 + x f32 -> out f32) — unchanged proven
// config (~11-13 us, VGPR 60). Thread owns one f4 column, z-chunk 16 (24
// iters, amp 1.5), 9-deep f32 ring; named depth-2 chains on t2 and x.
// Grid: 1024 blocks x 4 waves; chunks 2*xcd..2*xcd+1 match the writer band.
// ---------------------------------------------------------------------------
__global__ __launch_bounds__(256) void d_clip_pass(const __half* __restrict__ t2,
                                                   const float* __restrict__ x,
                                                   float* __restrict__ out, W9 wt) {
    const int bid   = blockIdx.x;
    const int xcd   = bid & 7;
    const int k     = bid >> 3;                  // 0..127
    const int chunk = xcd * 2 + (k & 1);         // 0..15, XCD-local
    const int tile  = k >> 1;                    // 0..63
    const int z0    = chunk * 16;
    const size_t c4 = (size_t)tile * 256 + threadIdx.x;   // f4-col in plane

    const half4*  t4 = (const half4*)t2;         // plane stride 16384 half4s
    const float4* xp = (const float4*)x;
    float4*       o4 = (float4*)out;

    float4 ring[9];

    half4 cur = t4[(size_t)reflect_idx(z0 - 4, 256) * 16384 + c4];
    half4 nxt = t4[(size_t)reflect_idx(z0 - 3, 256) * 16384 + c4];
    float4 xCur, xNxt;

    #pragma unroll
    for (int i = 0; i < 24; ++i) {
        half4 nn;
        if (i < 22)
            nn = t4[(size_t)reflect_idx(z0 - 2 + i, 256) * 16384 + c4];
        float4 xNew;
        if (i >= 6 && i < 22)   // x plane z0+i-6, consumed at iter i+2
            xNew = xp[(size_t)(z0 + i - 6) * 16384 + c4];

        ring[i % 9] = h4_to_f4(cur);   // plane z0-4+i

        if (i >= 8) {
            const int z = z0 + i - 8;
            float a0 = 0.f, a1 = 0.f, a2 = 0.f, a3 = 0.f;
            #pragma unroll
            for (int j = 0; j < 9; ++j) {
                const float4 v = ring[(i - 8 + j) % 9];
                a0 = fmaf(wt.g[j], v.x, a0);
                a1 = fmaf(wt.g[j], v.y, a1);
                a2 = fmaf(wt.g[j], v.z, a2);
                a3 = fmaf(wt.g[j], v.w, a3);
            }
            const float4 xv = xCur;    // x plane z (loaded at iter i-2)
            float4 r;
            r.x = fmaxf(fminf(xv.x, a0 + CLIPV), a0 - CLIPV);
            r.y = fmaxf(fminf(xv.y, a1 + CLIPV), a1 - CLIPV);
            r.z = fmaxf(fminf(xv.z, a2 + CLIPV), a2 - CLIPV);
            r.w = fmaxf(fminf(xv.w, a3 + CLIPV), a3 - CLIPV);
            o4[(size_t)z * 16384 + c4] = r;
        }

        cur = nxt; nxt = nn;
        xCur = xNxt; xNxt = xNew;
    }
}

extern "C" void kernel_launch(void* const* d_in, const int* in_sizes, int n_in,
                              void* d_out, int out_size, void* d_ws, size_t ws_size,
                              hipStream_t stream) {
    const float* x = (const float*)d_in[0];
    float* out = (float*)d_out;
    __half* t2 = (__half*)d_ws;            // 32 MB (single fp16 intermediate)

    // normalized 1-D Gaussian weights (separable form of the reference kernel)
    W9 wt;
    {
        double g[9], s = 0.0;
        const double sigma = 9.0 / 4.0;
        for (int i = 0; i < 9; ++i) {
            double tt = (i - 4.0) / sigma;
            g[i] = exp(-0.5 * tt * tt);
            s += g[i];
        }
        for (int i = 0; i < 9; ++i) wt.g[i] = (float)(g[i] / s);
    }

    wh_pass<<<dim3(1024), dim3(256), 0, stream>>>(x, t2, wt);
    d_clip_pass<<<dim3(1024), dim3(256), 0, stream>>>(t2, x, out, wt);
}

// Round 24
// 52.907 us; speedup vs baseline: 1.0143x; 1.0143x over previous
//
#include <hip/hip_runtime.h>
#include <hip/hip_fp16.h>
#include <math.h>

#define CLIPV 0.03f

struct W9 { float g[9]; };
struct half4 { __half2 a, b; };   // 8 bytes, 2 VGPRs

__device__ __forceinline__ int reflect_idx(int i, int n) {
    if (i < 0) i = -i;
    if (i >= n) i = 2 * n - 2 - i;
    return i;
}

__device__ __forceinline__ float4 h4_to_f4(half4 v) {
    const float2 ab = __half22float2(v.a), cd = __half22float2(v.b);
    float4 r; r.x = ab.x; r.y = ab.y; r.z = cd.x; r.w = cd.y; return r;
}
__device__ __forceinline__ half4 f4_to_h4(float4 v) {
    half4 r; r.a = __floats2half2_rn(v.x, v.y); r.b = __floats2half2_rn(v.z, v.w);
    return r;
}

// ---------------------------------------------------------------------------
// Pass 1: W+H fused via ASYNC DMA row staging (x f32 -> t2 fp16).
// Mechanism change vs all 41-us variants: rows are staged with
// __builtin_amdgcn_global_load_lds (16B/lane direct-to-LDS DMA). The DMA
// issues where written — the register allocator CANNOT sink it to its use
// (the failure mode R14/R16 proved for register staging). Completion is
// enforced by counted `s_waitcnt vmcnt(N)` (never 0 — loads stay in flight
// across iterations) + sched_barrier (compiler may not hoist the ds_reads
// above the wait). The staged row also provides the W window cross-lane for
// free (3x ds_read_b128, 2-way alias; R23-validated edge select table).
// Per wave: 4-slot rotating row buffer (4x256 floats, wave-private; slot
// overwritten a full iteration after its last read). LDS dest = wave-uniform
// base + lane*16 (exactly the HW constraint); global src = per-lane row+w4.
// Per iter vm ops: 1 DMA + (i>=8) 1 store. Static count of ops younger than
// row i's DMA at the wait point: i<=8: 2 (loads i+1,i+2); i in 9..22: 3
// (+store i-1); i==23: 2 (stores i-1,i-2... loads done) -> vmcnt(2).
// Wave = 16 output rows of one z-plane; 24 iters (amp 1.5).
// Grid: 1024 blocks x 4 waves = 16 waves/CU. bid&7 = XCD z-band.
// ---------------------------------------------------------------------------
__global__ __launch_bounds__(256) void wh_pass(const float* __restrict__ x,
                                               __half* __restrict__ t2, W9 wt) {
    __shared__ float stage[4][4][256];   // [wave][slot][row floats] = 16 KB

    const int bid = blockIdx.x;
    const int xcd = bid & 7;
    const int k   = bid >> 3;              // 0..127
    const int z   = xcd * 32 + (k >> 2);   // XCD-local z band
    const int wv  = threadIdx.x >> 6;
    const int h0  = ((k & 3) * 4 + wv) * 16;   // this wave's 16 output rows
    const int L   = threadIdx.x & 63;
    const int w4  = L * 4;
    const bool l0 = (L == 0), l63 = (L == 63);

    const float* plane  = x  + (size_t)z * 65536;
    __half*      oplane = t2 + (size_t)z * 65536;

    // issue one row DMA: global row (per-lane src) -> stage[wv][slot] (uniform base)
    auto dma_row = [&](int i, int slot) {
        const float* src = plane + (size_t)reflect_idx(h0 - 4 + i, 256) * 256 + w4;
        __builtin_amdgcn_global_load_lds(
            (const __attribute__((address_space(1))) unsigned int*)src,
            (__attribute__((address_space(3))) unsigned int*)&stage[wv][slot][0],
            16, 0, 0);
    };

    float4 ring[9];

    // prologue: rows 0,1 in flight
    dma_row(0, 0);
    dma_row(1, 1);

    // window read offsets (floats within the row); edge lanes use dummies +
    // the R23-validated select table
    const int offA = l0  ? w4 : (w4 - 4);
    const int offC = l63 ? w4 : (w4 + 4);

    #pragma unroll
    for (int i = 0; i < 24; ++i) {
        // issue DMA of row i+2 into slot (i+2)%4 (reuse distance: slot
        // (i+2)%4 was last read at iter i-2 — a full iteration of slack)
        if (i < 22) dma_row(i + 2, (i + 2) & 3);

        // counted wait: row i's DMA complete; younger ops stay in flight
        if (i <= 8 || i == 23) asm volatile("s_waitcnt vmcnt(2)" ::: "memory");
        else                   asm volatile("s_waitcnt vmcnt(3)" ::: "memory");
        __builtin_amdgcn_sched_barrier(0);

        // ---- W window from the staged row ----
        const float* rowp = &stage[wv][i & 3][0];
        const float4 A = *(const float4*)(rowp + offA);
        const float4 B = *(const float4*)(rowp + w4);
        const float4 C = *(const float4*)(rowp + offC);

        float sv[12];
        sv[0] = l0 ? C.x : A.x;   // col -4 -> 4  (lane0: C = cols 4..7)
        sv[1] = l0 ? B.w : A.y;   // col -3 -> 3
        sv[2] = l0 ? B.z : A.z;   // col -2 -> 2
        sv[3] = l0 ? B.y : A.w;   // col -1 -> 1
        sv[4] = B.x; sv[5] = B.y; sv[6] = B.z; sv[7] = B.w;
        sv[8]  = l63 ? B.z : C.x; // col 256 -> 254
        sv[9]  = l63 ? B.y : C.y; // col 257 -> 253
        sv[10] = l63 ? B.x : C.z; // col 258 -> 252
        sv[11] = l63 ? A.w : C.w; // col 259 -> 251 (lane63: A = 248..251)

        // ---- W-conv -> ring (static index after full unroll) ----
        {
            float a0 = 0.f, a1 = 0.f, a2 = 0.f, a3 = 0.f;
            #pragma unroll
            for (int j = 0; j < 9; ++j) {
                a0 = fmaf(wt.g[j], sv[j],     a0);
                a1 = fmaf(wt.g[j], sv[j + 1], a1);
                a2 = fmaf(wt.g[j], sv[j + 2], a2);
                a3 = fmaf(wt.g[j], sv[j + 3], a3);
            }
            float4 wc; wc.x = a0; wc.y = a1; wc.z = a2; wc.w = a3;
            ring[i % 9] = wc;
        }

        // ---- H-conv once ring holds rows hout-4..hout+4; store ----
        if (i >= 8) {
            float a0 = 0.f, a1 = 0.f, a2 = 0.f, a3 = 0.f;
            #pragma unroll
            for (int j = 0; j < 9; ++j) {
                const float4 v = ring[(i - 8 + j) % 9];
                a0 = fmaf(wt.g[j], v.x, a0);
                a1 = fmaf(wt.g[j], v.y, a1);
                a2 = fmaf(wt.g[j], v.z, a2);
                a3 = fmaf(wt.g[j], v.w, a3);
            }
            float4 o; o.x = a0; o.y = a1; o.z = a2; o.w = a3;
            *(half4*)(oplane + (size_t)(h0 + i - 8) * 256 + w4) = f4_to_h4(o);
        }
    }
}

// ---------------------------------------------------------------------------
// Pass 2: D-conv + clip (t2 fp16 + x f32 -> out f32) — unchanged proven
// config (~11-13 us, VGPR 60). Thread owns one f4 column, z-chunk 16 (24
// iters, amp 1.5), 9-deep f32 ring; named depth-2 chains on t2 and x.
// Grid: 1024 blocks x 4 waves; chunks 2*xcd..2*xcd+1 match the writer band.
// ---------------------------------------------------------------------------
__global__ __launch_bounds__(256) void d_clip_pass(const __half* __restrict__ t2,
                                                   const float* __restrict__ x,
                                                   float* __restrict__ out, W9 wt) {
    const int bid   = blockIdx.x;
    const int xcd   = bid & 7;
    const int k     = bid >> 3;                  // 0..127
    const int chunk = xcd * 2 + (k & 1);         // 0..15, XCD-local
    const int tile  = k >> 1;                    // 0..63
    const int z0    = chunk * 16;
    const size_t c4 = (size_t)tile * 256 + threadIdx.x;   // f4-col in plane

    const half4*  t4 = (const half4*)t2;         // plane stride 16384 half4s
    const float4* xp = (const float4*)x;
    float4*       o4 = (float4*)out;

    float4 ring[9];

    half4 cur = t4[(size_t)reflect_idx(z0 - 4, 256) * 16384 + c4];
    half4 nxt = t4[(size_t)reflect_idx(z0 - 3, 256) * 16384 + c4];
    float4 xCur, xNxt;

    #pragma unroll
    for (int i = 0; i < 24; ++i) {
        half4 nn;
        if (i < 22)
            nn = t4[(size_t)reflect_idx(z0 - 2 + i, 256) * 16384 + c4];
        float4 xNew;
        if (i >= 6 && i < 22)   // x plane z0+i-6, consumed at iter i+2
            xNew = xp[(size_t)(z0 + i - 6) * 16384 + c4];

        ring[i % 9] = h4_to_f4(cur);   // plane z0-4+i

        if (i >= 8) {
            const int z = z0 + i - 8;
            float a0 = 0.f, a1 = 0.f, a2 = 0.f, a3 = 0.f;
            #pragma unroll
            for (int j = 0; j < 9; ++j) {
                const float4 v = ring[(i - 8 + j) % 9];
                a0 = fmaf(wt.g[j], v.x, a0);
                a1 = fmaf(wt.g[j], v.y, a1);
                a2 = fmaf(wt.g[j], v.z, a2);
                a3 = fmaf(wt.g[j], v.w, a3);
            }
            const float4 xv = xCur;    // x plane z (loaded at iter i-2)
            float4 r;
            r.x = fmaxf(fminf(xv.x, a0 + CLIPV), a0 - CLIPV);
            r.y = fmaxf(fminf(xv.y, a1 + CLIPV), a1 - CLIPV);
            r.z = fmaxf(fminf(xv.z, a2 + CLIPV), a2 - CLIPV);
            r.w = fmaxf(fminf(xv.w, a3 + CLIPV), a3 - CLIPV);
            o4[(size_t)z * 16384 + c4] = r;
        }

        cur = nxt; nxt = nn;
        xCur = xNxt; xNxt = xNew;
    }
}

extern "C" void kernel_launch(void* const* d_in, const int* in_sizes, int n_in,
                              void* d_out, int out_size, void* d_ws, size_t ws_size,
                              hipStream_t stream) {
    const float* x = (const float*)d_in[0];
    float* out = (float*)d_out;
    __half* t2 = (__half*)d_ws;            // 32 MB (single fp16 intermediate)

    // normalized 1-D Gaussian weights (separable form of the reference kernel)
    W9 wt;
    {
        double g[9], s = 0.0;
        const double sigma = 9.0 / 4.0;
        for (int i = 0; i < 9; ++i) {
            double tt = (i - 4.0) / sigma;
            g[i] = exp(-0.5 * tt * tt);
            s += g[i];
        }
        for (int i = 0; i < 9; ++i) wt.g[i] = (float)(g[i] / s);
    }

    wh_pass<<<dim3(1024), dim3(256), 0, stream>>>(x, t2, wt);
    d_clip_pass<<<dim3(1024), dim3(256), 0, stream>>>(t2, x, out, wt);
}

// Round 25
// 52.000 us; speedup vs baseline: 1.0320x; 1.0174x over previous
//
#include <hip/hip_runtime.h>
#include <hip/hip_fp16.h>
#include <math.h>

#define CLIPV 0.03f

struct W9 { float g[9]; };
struct half4 { __half2 a, b; };   // 8 bytes, 2 VGPRs

__device__ __forceinline__ int reflect_idx(int i, int n) {
    if (i < 0) i = -i;
    if (i >= n) i = 2 * n - 2 - i;
    return i;
}

__device__ __forceinline__ float4 h4_to_f4(half4 v) {
    const float2 ab = __half22float2(v.a), cd = __half22float2(v.b);
    float4 r; r.x = ab.x; r.y = ab.y; r.z = cd.x; r.w = cd.y; return r;
}
__device__ __forceinline__ half4 f4_to_h4(float4 v) {
    half4 r; r.a = __floats2half2_rn(v.x, v.y); r.b = __floats2half2_rn(v.z, v.w);
    return r;
}
__device__ __forceinline__ float4 shfl_up1(float4 v) {
    float4 r;
    r.x = __shfl_up(v.x, 1); r.y = __shfl_up(v.y, 1);
    r.z = __shfl_up(v.z, 1); r.w = __shfl_up(v.w, 1);
    return r;
}

// ---------------------------------------------------------------------------
// Pass 1: W+H fused (x f32 -> t2 fp16), hybrid window sourcing — the best-
// measured variant (R22, 51.89 us total). NOTE (R24 conclusion): this pass
// occupies the harness-gated first-kernel slot (~41 us regardless of kernel
// structure — 8 distinct mechanisms all measured 41±1; the slot is gated by
// the inter-replay 268 MB poison-fill sweeping/dirtying L3). Chosen variant
// is the simplest correct one: 2 global streams + shfl-derived left window.
// Wave = 16 output rows of one z-plane; 24 iters (amp 1.5).
// Grid: 1024 blocks x 4 waves = 16 waves/CU. bid&7 = XCD z-band.
// ---------------------------------------------------------------------------
__global__ __launch_bounds__(256, 4) void wh_pass(const float* __restrict__ x,
                                                  __half* __restrict__ t2, W9 wt) {
    const int bid = blockIdx.x;
    const int xcd = bid & 7;
    const int k   = bid >> 3;                       // 0..127
    const int z   = xcd * 32 + (k >> 2);            // XCD-local z band
    const int wv  = threadIdx.x >> 6;
    const int h0  = ((k & 3) * 4 + wv) * 16;        // 16 output rows
    const int L   = threadIdx.x & 63;
    const int w4  = L * 4;
    const bool l0 = (L == 0), l63 = (L == 63);
    const int offR = l63 ? 251 : (w4 + 4);  // lane 63 loads 251..254, reversed

    const float* plane  = x  + (size_t)z * 65536;
    __half*      oplane = t2 + (size_t)z * 65536;

    float4 ring[9];

    // named depth-2 staging chains (consume c*, next n*, incoming m*)
    float4 cCf, cRf, nCf, nRf;
    {
        const float* r0 = plane + (size_t)reflect_idx(h0 - 4, 256) * 256;
        cCf = *(const float4*)(r0 + w4);
        cRf = *(const float4*)(r0 + offR);
        const float* r1 = plane + (size_t)reflect_idx(h0 - 3, 256) * 256;
        nCf = *(const float4*)(r1 + w4);
        nRf = *(const float4*)(r1 + offR);
    }

    #pragma unroll
    for (int i = 0; i < 24; ++i) {
        float4 mCf, mRf;
        if (i < 22) {
            const float* row = plane + (size_t)reflect_idx(h0 - 2 + i, 256) * 256;
            mCf = *(const float4*)(row + w4);
            mRf = *(const float4*)(row + offR);
        }

        // ---- left window via shuffle of the long-arrived cC ----
        const float4 cLf = shfl_up1(cCf);   // lane L-1's cols w-4..w-1

        // ---- W-conv of row h0-4+i ----
        float sv[12];
        sv[0] = l0 ? cRf.x : cLf.x;   // col -4 -> 4  (lane0: cR = cols 4..7)
        sv[1] = l0 ? cCf.w : cLf.y;   // col -3 -> 3
        sv[2] = l0 ? cCf.z : cLf.z;   // col -2 -> 2
        sv[3] = l0 ? cCf.y : cLf.w;   // col -1 -> 1
        sv[4] = cCf.x; sv[5] = cCf.y; sv[6] = cCf.z; sv[7] = cCf.w;
        sv[8]  = l63 ? cRf.w : cRf.x; // col 256 -> 254 (lane63: cR=251..254 rev)
        sv[9]  = l63 ? cRf.z : cRf.y; // col 257 -> 253
        sv[10] = l63 ? cRf.y : cRf.z; // col 258 -> 252
        sv[11] = l63 ? cRf.x : cRf.w; // col 259 -> 251

        {
            float a0 = 0.f, a1 = 0.f, a2 = 0.f, a3 = 0.f;
            #pragma unroll
            for (int j = 0; j < 9; ++j) {
                a0 = fmaf(wt.g[j], sv[j],     a0);
                a1 = fmaf(wt.g[j], sv[j + 1], a1);
                a2 = fmaf(wt.g[j], sv[j + 2], a2);
                a3 = fmaf(wt.g[j], sv[j + 3], a3);
            }
            float4 wc; wc.x = a0; wc.y = a1; wc.z = a2; wc.w = a3;
            ring[i % 9] = wc;   // static index after full unroll
        }

        // ---- H-conv once ring holds rows hout-4..hout+4 ----
        if (i >= 8) {
            float a0 = 0.f, a1 = 0.f, a2 = 0.f, a3 = 0.f;
            #pragma unroll
            for (int j = 0; j < 9; ++j) {
                const float4 v = ring[(i - 8 + j) % 9];
                a0 = fmaf(wt.g[j], v.x, a0);
                a1 = fmaf(wt.g[j], v.y, a1);
                a2 = fmaf(wt.g[j], v.z, a2);
                a3 = fmaf(wt.g[j], v.w, a3);
            }
            float4 o; o.x = a0; o.y = a1; o.z = a2; o.w = a3;
            *(half4*)(oplane + (size_t)(h0 + i - 8) * 256 + w4) = f4_to_h4(o);
        }

        cCf = nCf; cRf = nRf;
        nCf = mCf; nRf = mRf;
    }
}

// ---------------------------------------------------------------------------
// Pass 2: D-conv + clip (t2 fp16 + x f32 -> out f32) — proven config (~11 us,
// VGPR 60; runs L3-hot at ~14.5 TB/s effective, near its 160 MB byte floor).
// Thread owns one f4 column, z-chunk 16 (24 iters, amp 1.5), 9-deep f32
// ring; named depth-2 chains on t2 and x.
// Grid: 1024 blocks x 4 waves; chunks 2*xcd..2*xcd+1 match the writer band.
// ---------------------------------------------------------------------------
__global__ __launch_bounds__(256) void d_clip_pass(const __half* __restrict__ t2,
                                                   const float* __restrict__ x,
                                                   float* __restrict__ out, W9 wt) {
    const int bid   = blockIdx.x;
    const int xcd   = bid & 7;
    const int k     = bid >> 3;                  // 0..127
    const int chunk = xcd * 2 + (k & 1);         // 0..15, XCD-local
    const int tile  = k >> 1;                    // 0..63
    const int z0    = chunk * 16;
    const size_t c4 = (size_t)tile * 256 + threadIdx.x;   // f4-col in plane

    const half4*  t4 = (const half4*)t2;         // plane stride 16384 half4s
    const float4* xp = (const float4*)x;
    float4*       o4 = (float4*)out;

    float4 ring[9];

    half4 cur = t4[(size_t)reflect_idx(z0 - 4, 256) * 16384 + c4];
    half4 nxt = t4[(size_t)reflect_idx(z0 - 3, 256) * 16384 + c4];
    float4 xCur, xNxt;

    #pragma unroll
    for (int i = 0; i < 24; ++i) {
        half4 nn;
        if (i < 22)
            nn = t4[(size_t)reflect_idx(z0 - 2 + i, 256) * 16384 + c4];
        float4 xNew;
        if (i >= 6 && i < 22)   // x plane z0+i-6, consumed at iter i+2
            xNew = xp[(size_t)(z0 + i - 6) * 16384 + c4];

        ring[i % 9] = h4_to_f4(cur);   // plane z0-4+i

        if (i >= 8) {
            const int z = z0 + i - 8;
            float a0 = 0.f, a1 = 0.f, a2 = 0.f, a3 = 0.f;
            #pragma unroll
            for (int j = 0; j < 9; ++j) {
                const float4 v = ring[(i - 8 + j) % 9];
                a0 = fmaf(wt.g[j], v.x, a0);
                a1 = fmaf(wt.g[j], v.y, a1);
                a2 = fmaf(wt.g[j], v.z, a2);
                a3 = fmaf(wt.g[j], v.w, a3);
            }
            const float4 xv = xCur;    // x plane z (loaded at iter i-2)
            float4 r;
            r.x = fmaxf(fminf(xv.x, a0 + CLIPV), a0 - CLIPV);
            r.y = fmaxf(fminf(xv.y, a1 + CLIPV), a1 - CLIPV);
            r.z = fmaxf(fminf(xv.z, a2 + CLIPV), a2 - CLIPV);
            r.w = fmaxf(fminf(xv.w, a3 + CLIPV), a3 - CLIPV);
            o4[(size_t)z * 16384 + c4] = r;
        }

        cur = nxt; nxt = nn;
        xCur = xNxt; xNxt = xNew;
    }
}

extern "C" void kernel_launch(void* const* d_in, const int* in_sizes, int n_in,
                              void* d_out, int out_size, void* d_ws, size_t ws_size,
                              hipStream_t stream) {
    const float* x = (const float*)d_in[0];
    float* out = (float*)d_out;
    __half* t2 = (__half*)d_ws;            // 32 MB (single fp16 intermediate)

    // normalized 1-D Gaussian weights (separable form of the reference kernel)
    W9 wt;
    {
        double g[9], s = 0.0;
        const double sigma = 9.0 / 4.0;
        for (int i = 0; i < 9; ++i) {
            double tt = (i - 4.0) / sigma;
            g[i] = exp(-0.5 * tt * tt);
            s += g[i];
        }
        for (int i = 0; i < 9; ++i) wt.g[i] = (float)(g[i] / s);
    }

    wh_pass<<<dim3(1024), dim3(256), 0, stream>>>(x, t2, wt);
    d_clip_pass<<<dim3(1024), dim3(256), 0, stream>>>(t2, x, out, wt);
}